// Round 2
// baseline (698.742 us; speedup 1.0000x reference)
//
#include <hip/hip_runtime.h>
#include <hip/hip_cooperative_groups.h>
#include <math.h>

namespace cg = cooperative_groups;

#define N_NODES 50000
#define N_EDGES 600000
#define NFEAT   256
#define NHID    128
#define NCLASS  40
#define NBUCK 196            // bucket = dst >> 8 (256-node windows)
#define EPB_A 2048           // edges per phase-A virtual block
#define BUCK_CAP 4096        // staging capacity per bucket (mean ~3062)
#define BUCK_WIN 5888        // fixed CSR window per bucket >= BUCK_CAP + 7*256
#define BINA_VB ((N_EDGES + EPB_A - 1) / EPB_A)   // 293
#define CVTW_VB 224                               // 57344 weight elems / 256
#define GEMM_VB ((N_NODES + 63) / 64)             // 782
#define SPMM_VB ((N_NODES + 3) / 4)               // 12500

typedef __attribute__((ext_vector_type(8))) short bf16x8;
typedef __attribute__((ext_vector_type(4))) float f32x4;
typedef __attribute__((ext_vector_type(2))) float f32x2;

__device__ inline ushort f2bf(float f) {   // RNE, finite inputs
    uint u = __float_as_uint(f);
    uint r = (u + 0x7fffu + ((u >> 16) & 1u)) >> 16;
    return (ushort)r;
}

struct Params {
    const int* esrc; const int* edst; const float* ew;
    const float* W1; const float* b1;
    const float* W2; const float* b2;
    const float* W3; const float* b3;
    const float* x; float* out;
    int* bucket_cnt; int2* rsp2; uint* edges; int2* staging;
    ushort* BT1; ushort* BT2; ushort* BT3;
    ushort* supA; ushort* hA; ushort* supB; ushort* hB; ushort* sup3;
};

struct SMem {
    union {
        int lh[NBUCK];                                        // binA
        struct { int hist[256]; int buf[256]; int lcur[256]; } sc;  // scan
        struct { ushort a_s[64 * 40]; ushort b_s[128 * 40]; } ge;   // gemm
    } u;
};

// ---------------------------------------------------------------------------
// Phase A worker: bin edges by 256-node bucket into fixed-capacity staging.
// Record: uint = (bf16(w)<<16) | src; staging entry {rec, dst&255}.
__device__ __forceinline__ void binA_body(const Params& P, int vb, SMem& sm) {
    int tid = threadIdx.x;
    int* lh = sm.u.lh;
    for (int b = tid; b < NBUCK; b += 256) lh[b] = 0;
    __syncthreads();
    int base = vb * EPB_A;
    int d[8];
    #pragma unroll
    for (int j = 0; j < 8; ++j) {
        int i = base + j * 256 + tid;
        d[j] = (i < N_EDGES) ? P.edst[i] : -1;
        if (d[j] >= 0) atomicAdd(&lh[d[j] >> 8], 1);
    }
    __syncthreads();
    for (int b = tid; b < NBUCK; b += 256) {
        int c = lh[b];
        lh[b] = c ? (b * BUCK_CAP + atomicAdd(&P.bucket_cnt[b], c)) : 0;
    }
    __syncthreads();
    #pragma unroll
    for (int j = 0; j < 8; ++j) {
        int i = base + j * 256 + tid;
        if (d[j] >= 0) {
            int slot = atomicAdd(&lh[d[j] >> 8], 1);
            uint rec = ((uint)f2bf(P.ew[i]) << 16) | (uint)P.esrc[i];
            P.staging[slot] = make_int2((int)rec, d[j] & 255);
        }
    }
    __syncthreads();   // LDS safe for next virtual block
}

// Phase A worker: transpose+convert the three weight matrices to bf16.
__device__ __forceinline__ void cvtw_body(const Params& P, int vb) {
    int idx = vb * 256 + (int)threadIdx.x;
    if (idx < 32768) {                       // BT1: 128x256 from W1[256x128]
        int nr = idx >> 8, k = idx & 255;
        P.BT1[idx] = f2bf(P.W1[(size_t)k * 128 + nr]);
    } else if (idx < 49152) {                // BT2: 128x128 from W2[128x128]
        int t = idx - 32768;
        int nr = t >> 7, k = t & 127;
        P.BT2[t] = f2bf(P.W2[(size_t)k * 128 + nr]);
    } else if (idx < 57344) {                // BT3: 64x128 from W3[128x40], zero-pad
        int t = idx - 49152;
        int nr = t >> 7, k = t & 127;
        P.BT3[t] = (nr < 40) ? f2bf(P.W3[(size_t)k * 40 + nr]) : (ushort)0;
    }
}

// Phase B worker: self-contained per-bucket scan+scatter into FIXED windows
// (base = b*BUCK_WIN; inter-bucket gaps never read -> no global prefix).
__device__ __forceinline__ void scan_body(const Params& P, int b, SMem& sm) {
    int tid = threadIdx.x;
    int* hist = sm.u.sc.hist;
    int* buf  = sm.u.sc.buf;
    int* lcur = sm.u.sc.lcur;
    hist[tid] = 0;
    __syncthreads();
    int c = P.bucket_cnt[b];
    const int2* st = P.staging + (size_t)b * BUCK_CAP;
    for (int p = tid; p < c; p += 256) atomicAdd(&hist[st[p].y], 1);
    __syncthreads();
    int v = (hist[tid] + 7) & ~7;   // pad per-node count to multiple of 8
    buf[tid] = v;
    __syncthreads();
    #pragma unroll
    for (int off = 1; off < 256; off <<= 1) {
        int t = (tid >= off) ? buf[tid - off] : 0;
        __syncthreads();
        buf[tid] += t;
        __syncthreads();
    }
    int bb = b * BUCK_WIN;
    int ex = buf[tid] - v + bb;
    int i = b * 256 + tid;
    if (i < N_NODES) P.rsp2[i] = make_int2(ex, ex + v);
    lcur[tid] = ex;
    __syncthreads();
    int e0 = bb + buf[255];
    for (int p = bb + tid; p < e0; p += 256) P.edges[p] = 0;   // covers padding
    __syncthreads();
    for (int p = tid; p < c; p += 256) {
        int2 r = st[p];
        int slot = atomicAdd(&lcur[r.y], 1);
        P.edges[slot] = (uint)r.x;
    }
    __syncthreads();   // LDS safe for whatever comes next on this block
}

// ---------------------------------------------------------------------------
// bf16 MFMA GEMM: C[M x Nout] = A[M x K] @ BT[.. x K]^T, one 64-row tile.
template<int NT, bool OUTBF, bool AF32>
__device__ __forceinline__ void gemm_body(const void* __restrict__ Ain,
                                          const ushort* __restrict__ BT,
                                          int M, int K, int Nout,
                                          void* __restrict__ Cout, int row0,
                                          ushort* a_s, ushort* b_s) {
    int tid = threadIdx.x;
    int wave = tid >> 6, lane = tid & 63;
    int lr = lane & 15, lk = (lane >> 4) * 8;
    f32x4 acc[4][NT];
    #pragma unroll
    for (int mt = 0; mt < 4; ++mt)
        #pragma unroll
        for (int nt = 0; nt < NT; ++nt) acc[mt][nt] = (f32x4){0.f, 0.f, 0.f, 0.f};

    for (int k0 = 0; k0 < K; k0 += 32) {
        {   // A tile: 64 rows x 32 k, 8 elems/thread
            int r = tid >> 2, c8 = (tid & 3) * 8;
            int gr = row0 + r; if (gr >= M) gr = M - 1;  // clamp, store-guarded
            if (AF32) {
                const float* Af = (const float*)Ain;
                float4 v0 = *(const float4*)(Af + (size_t)gr * K + k0 + c8);
                float4 v1 = *(const float4*)(Af + (size_t)gr * K + k0 + c8 + 4);
                ushort4 o0, o1;
                o0.x = f2bf(v0.x); o0.y = f2bf(v0.y); o0.z = f2bf(v0.z); o0.w = f2bf(v0.w);
                o1.x = f2bf(v1.x); o1.y = f2bf(v1.y); o1.z = f2bf(v1.z); o1.w = f2bf(v1.w);
                *(ushort4*)(a_s + r * 40 + c8) = o0;
                *(ushort4*)(a_s + r * 40 + c8 + 4) = o1;
            } else {
                const ushort* Ab = (const ushort*)Ain;
                float4 v = *(const float4*)(Ab + (size_t)gr * K + k0 + c8);
                *(float4*)(a_s + r * 40 + c8) = v;
            }
        }
        #pragma unroll
        for (int i = 0; i < NT; ++i) {  // BT tile: 64*NT rows x 32 k
            int idx = tid * NT + i;
            int r = idx >> 2, c8 = (idx & 3) * 8;
            float4 v = *(const float4*)(BT + (size_t)r * K + k0 + c8);
            *(float4*)(b_s + r * 40 + c8) = v;
        }
        __syncthreads();
        bf16x8 bfr[NT];
        #pragma unroll
        for (int nt = 0; nt < NT; ++nt)
            bfr[nt] = *(const bf16x8*)(b_s + ((wave * NT + nt) * 16 + lr) * 40 + lk);
        #pragma unroll
        for (int mt = 0; mt < 4; ++mt) {
            bf16x8 afr = *(const bf16x8*)(a_s + (mt * 16 + lr) * 40 + lk);
            #pragma unroll
            for (int nt = 0; nt < NT; ++nt)
                acc[mt][nt] = __builtin_amdgcn_mfma_f32_16x16x32_bf16(
                    afr, bfr[nt], acc[mt][nt], 0, 0, 0);
        }
        __syncthreads();
    }
    // C/D layout: col = lane&15, row = (lane>>4)*4 + i
    int col0 = wave * NT * 16;
    #pragma unroll
    for (int mt = 0; mt < 4; ++mt) {
        int gr0 = row0 + mt * 16 + (lane >> 4) * 4;
        #pragma unroll
        for (int nt = 0; nt < NT; ++nt) {
            int gc = col0 + nt * 16 + lr;
            #pragma unroll
            for (int i = 0; i < 4; ++i) {
                int gr = gr0 + i;
                if (gr < M && gc < Nout) {
                    if (OUTBF)
                        ((ushort*)Cout)[(size_t)gr * Nout + gc] = f2bf(acc[mt][nt][i]);
                    else
                        ((float*)Cout)[(size_t)gr * Nout + gc] = acc[mt][nt][i];
                }
            }
        }
    }
}

// ---------------------------------------------------------------------------
// SpMM over bf16 support, F=128. Wave = 1 node, lane owns 2 features.
// Branch-free 8-edge groups, 8 independent gathers in flight (deep MLP),
// f32x2 accumulator -> one v_pk_fma_f32 per edge.
__device__ __forceinline__ void spmm128_body(const Params& P,
                                             const uint* __restrict__ sup,
                                             const float* __restrict__ bias,
                                             uint* __restrict__ outb,
                                             int wid, int lane) {
    int2 ke = P.rsp2[wid];
    int k = ke.x, e = ke.y;
    f32x2 acc = (f32x2){0.f, 0.f};
    if (k < e) {
        const uint4* q4 = (const uint4*)(P.edges + k);
        uint4 qa = q4[0], qb = q4[1];
        for (; k < e; k += 8) {
            int kn = k + 8;
            int kc = (kn < e) ? kn : k;          // clamp: reload current (L1 hit)
            const uint4* n4 = (const uint4*)(P.edges + kc);
            uint4 na = n4[0], nb = n4[1];        // prefetch next group
            uint q[8] = {qa.x, qa.y, qa.z, qa.w, qb.x, qb.y, qb.z, qb.w};
            uint p[8];
            #pragma unroll
            for (int j = 0; j < 8; ++j)
                p[j] = sup[(size_t)(q[j] & 0xffffu) * 64 + lane];
            #pragma unroll
            for (int j = 0; j < 8; ++j) {
                float w = __uint_as_float(q[j] & 0xffff0000u);  // bf16 bits -> f32
                f32x2 v;
                v.x = __uint_as_float(p[j] << 16);
                v.y = __uint_as_float(p[j] & 0xffff0000u);
                acc += v * (f32x2){w, w};
            }
            qa = na; qb = nb;
        }
    }
    float ax = fmaxf(acc.x + bias[lane * 2], 0.f);
    float ay = fmaxf(acc.y + bias[lane * 2 + 1], 0.f);
    outb[(size_t)wid * 64 + lane] = ((uint)f2bf(ay) << 16) | (uint)f2bf(ax);
}

// Layer 3: bf16 F=40 segment-sum + bias + log_softmax fused -> out (fp32)
__device__ __forceinline__ void spmm40_body(const Params& P, int wid, int lane) {
    int2 ke = P.rsp2[wid];
    int k = ke.x, e = ke.y;
    float acc = 0.f;
    int lf = (lane < 40) ? lane : 39;  // inactive lanes read lane 39 (no OOB)
    const ushort* sup = P.sup3;
    if (k < e) {
        const uint4* q4 = (const uint4*)(P.edges + k);
        uint4 qa = q4[0], qb = q4[1];
        for (; k < e; k += 8) {
            int kn = k + 8;
            int kc = (kn < e) ? kn : k;
            const uint4* n4 = (const uint4*)(P.edges + kc);
            uint4 na = n4[0], nb4 = n4[1];
            uint q[8] = {qa.x, qa.y, qa.z, qa.w, qb.x, qb.y, qb.z, qb.w};
            float p[8];
            #pragma unroll
            for (int j = 0; j < 8; ++j) {
                uint us = sup[(size_t)(q[j] & 0xffffu) * 40 + lf];
                p[j] = __uint_as_float(us << 16);
            }
            #pragma unroll
            for (int j = 0; j < 8; ++j)
                acc += p[j] * __uint_as_float(q[j] & 0xffff0000u);
            qa = na; qb = nb4;
        }
    }
    float v = (lane < 40) ? acc + P.b3[lane] : -INFINITY;
    float m = v;
    #pragma unroll
    for (int off = 32; off; off >>= 1) m = fmaxf(m, __shfl_xor(m, off, 64));
    float ex = (lane < 40) ? expf(v - m) : 0.f;
    float s = ex;
    #pragma unroll
    for (int off = 32; off; off >>= 1) s += __shfl_xor(s, off, 64);
    float ls = logf(s);
    if (lane < 40) P.out[(size_t)wid * 40 + lane] = v - m - ls;
}

// ---------------------------------------------------------------------------
// The whole pipeline as one cooperative kernel: 7 phases, 6 grid syncs,
// zero kernel boundaries. Work distributed grid-stride per phase.
__global__ __launch_bounds__(256) void mega(Params P) {
    __shared__ SMem sm;
    cg::grid_group grid = cg::this_grid();
    int tid = threadIdx.x;
    int nb = gridDim.x;

    // Phase A: edge binning (293) || weight conversion (224)
    for (int vb = blockIdx.x; vb < BINA_VB + CVTW_VB; vb += nb) {
        if (vb < BINA_VB) binA_body(P, vb, sm);
        else cvtw_body(P, vb - BINA_VB);
    }
    grid.sync();

    // Phase B: per-bucket scan+scatter (196) || GEMM1 (782)
    for (int vb = blockIdx.x; vb < NBUCK + GEMM_VB; vb += nb) {
        if (vb < NBUCK) scan_body(P, vb, sm);
        else gemm_body<2, true, true>(P.x, P.BT1, N_NODES, 256, 128, P.supA,
                                      (vb - NBUCK) * 64, sm.u.ge.a_s, sm.u.ge.b_s);
    }
    grid.sync();

    // Phase C: spmm layer 1 (+bias+relu)
    for (int vb = blockIdx.x; vb < SPMM_VB; vb += nb) {
        int wid = vb * 4 + (tid >> 6);
        if (wid < N_NODES)
            spmm128_body(P, (const uint*)P.supA, P.b1, (uint*)P.hA, wid, tid & 63);
    }
    grid.sync();

    // Phase D: GEMM2
    for (int vb = blockIdx.x; vb < GEMM_VB; vb += nb)
        gemm_body<2, true, false>(P.hA, P.BT2, N_NODES, 128, 128, P.supB,
                                  vb * 64, sm.u.ge.a_s, sm.u.ge.b_s);
    grid.sync();

    // Phase E: spmm layer 2 (+bias+relu)
    for (int vb = blockIdx.x; vb < SPMM_VB; vb += nb) {
        int wid = vb * 4 + (tid >> 6);
        if (wid < N_NODES)
            spmm128_body(P, (const uint*)P.supB, P.b2, (uint*)P.hB, wid, tid & 63);
    }
    grid.sync();

    // Phase F: GEMM3 (Nout=40)
    for (int vb = blockIdx.x; vb < GEMM_VB; vb += nb)
        gemm_body<1, true, false>(P.hB, P.BT3, N_NODES, 128, 40, P.sup3,
                                  vb * 64, sm.u.ge.a_s, sm.u.ge.b_s);
    grid.sync();

    // Phase G: spmm layer 3 + bias + log_softmax
    for (int vb = blockIdx.x; vb < SPMM_VB; vb += nb) {
        int wid = vb * 4 + (tid >> 6);
        if (wid < N_NODES) spmm40_body(P, wid, tid & 63);
    }
}

// ---------------------------------------------------------------------------
extern "C" void kernel_launch(void* const* d_in, const int* in_sizes, int n_in,
                              void* d_out, int out_size, void* d_ws, size_t ws_size,
                              hipStream_t stream) {
    char* ws = (char*)d_ws;
    size_t off = 0;
    auto alloc = [&](size_t bytes) {
        size_t cur = off;
        off += (bytes + 255) & ~(size_t)255;
        return cur;
    };
    int* bucket_cnt = (int*)(ws + alloc(256 * sizeof(int)));
    int2* rsp2   = (int2*)(ws + alloc((size_t)N_NODES * sizeof(int2)));          // 400 KB
    uint* edges  = (uint*)(ws + alloc((size_t)NBUCK * BUCK_WIN * sizeof(uint))); // 4.6 MB
    int2* staging = (int2*)(ws + alloc((size_t)NBUCK * BUCK_CAP * sizeof(int2))); // 6.4 MB
    ushort* BT1  = (ushort*)(ws + alloc(128 * 256 * 2));
    ushort* BT2  = (ushort*)(ws + alloc(128 * 128 * 2));
    ushort* BT3  = (ushort*)(ws + alloc(64 * 128 * 2));
    char* Sreg   = ws + alloc((size_t)N_NODES * 128 * 2);       // 12.8 MB
    char* Hreg   = ws + alloc((size_t)N_NODES * 128 * 2);       // 12.8 MB
    char* Treg   = ws + alloc((size_t)N_NODES * 128 * 2);       // 12.8 MB

    Params P;
    P.x   = (const float*)d_in[0];
    P.ew  = (const float*)d_in[1];
    P.W1  = (const float*)d_in[2];
    P.b1  = (const float*)d_in[3];
    P.W2  = (const float*)d_in[4];
    P.b2  = (const float*)d_in[5];
    P.W3  = (const float*)d_in[6];
    P.b3  = (const float*)d_in[7];
    P.esrc = (const int*)d_in[8];
    P.edst = (const int*)d_in[9];
    P.out = (float*)d_out;
    P.bucket_cnt = bucket_cnt;
    P.rsp2 = rsp2;
    P.edges = edges;
    P.staging = staging;
    P.BT1 = BT1; P.BT2 = BT2; P.BT3 = BT3;
    P.supA = (ushort*)Sreg;                  // gemm1 out
    P.hA   = (ushort*)Hreg;                  // spmm1 out
    P.supB = (ushort*)Treg;                  // gemm2 out
    P.hB   = (ushort*)Sreg;                  // spmm2 out (supA dead)
    P.sup3 = (ushort*)Treg;                  // gemm3 out F=40 (supB dead)

    // co-resident grid size (computed once; host-only, capture-safe)
    static int s_nblk = 0;
    if (s_nblk == 0) {
        int maxb = 0;
        hipError_t err = hipOccupancyMaxActiveBlocksPerMultiprocessor(&maxb, mega,
                                                                      256, (size_t)0);
        if (err != hipSuccess || maxb < 1) maxb = 2;   // conservative fallback
        if (maxb > 8) maxb = 8;
        s_nblk = maxb * 256;                           // 256 CUs on MI355X
    }

    hipMemsetAsync(bucket_cnt, 0, 256 * sizeof(int), stream);
    void* kargs[] = { &P };
    hipLaunchCooperativeKernel(mega, dim3(s_nblk), dim3(256), kargs, 0, stream);
}

// Round 3
// 231.209 us; speedup vs baseline: 3.0221x; 3.0221x over previous
//
#include <hip/hip_runtime.h>
#include <math.h>

#define N_NODES 50000
#define N_EDGES 600000
#define NFEAT   256
#define NHID    128
#define NCLASS  40
#define NBUCK 196            // bucket = dst >> 8 (256-node windows)
#define EPB_A 2048           // edges per phase-A block
#define BUCK_CAP 4096        // staging capacity per bucket (mean ~3062)
#define BUCK_WIN 5888        // fixed CSR window per bucket >= BUCK_CAP + 7*256 (mult of 8)
#define BINA_BLOCKS ((N_EDGES + EPB_A - 1) / EPB_A)   // 293
#define CVTW_BLOCKS 224                               // 57344 weight elems / 256
#define GEMM_BLOCKS ((N_NODES + 63) / 64)             // 782

typedef __attribute__((ext_vector_type(8))) short bf16x8;
typedef __attribute__((ext_vector_type(4))) float f32x4;
typedef __attribute__((ext_vector_type(2))) float f32x2;

__device__ inline ushort f2bf(float f) {   // RNE, finite inputs
    uint u = __float_as_uint(f);
    uint r = (u + 0x7fffu + ((u >> 16) & 1u)) >> 16;
    return (ushort)r;
}

// ---------------------------------------------------------------------------
// K1: blocks [0, BINA_BLOCKS) bin edges by 256-node bucket into fixed-capacity
// staging regions (record: uint = (bf16(w)<<16) | src; entry {rec, dst&255}).
// Blocks [BINA_BLOCKS, +CVTW_BLOCKS) convert the three weight matrices to
// transposed bf16.
__global__ __launch_bounds__(256) void binA_cvtw(const int* __restrict__ src,
                                                 const int* __restrict__ dst,
                                                 const float* __restrict__ w,
                                                 int* __restrict__ bucket_cnt,
                                                 int2* __restrict__ staging, int E,
                                                 const float* __restrict__ W1,
                                                 const float* __restrict__ W2,
                                                 const float* __restrict__ W3,
                                                 ushort* __restrict__ BT1,
                                                 ushort* __restrict__ BT2,
                                                 ushort* __restrict__ BT3) {
    int tid = threadIdx.x;
    if ((int)blockIdx.x >= BINA_BLOCKS) {
        int idx = ((int)blockIdx.x - BINA_BLOCKS) * 256 + tid;
        if (idx < 32768) {                       // BT1: 128x256 from W1[256x128]
            int nr = idx >> 8, k = idx & 255;
            BT1[idx] = f2bf(W1[(size_t)k * 128 + nr]);
        } else if (idx < 49152) {                // BT2: 128x128 from W2[128x128]
            int t = idx - 32768;
            int nr = t >> 7, k = t & 127;
            BT2[t] = f2bf(W2[(size_t)k * 128 + nr]);
        } else if (idx < 57344) {                // BT3: 64x128 from W3[128x40], zero-pad
            int t = idx - 49152;
            int nr = t >> 7, k = t & 127;
            BT3[t] = (nr < 40) ? f2bf(W3[(size_t)k * 40 + nr]) : (ushort)0;
        }
        return;
    }
    __shared__ int lh[NBUCK];
    for (int b = tid; b < NBUCK; b += 256) lh[b] = 0;
    __syncthreads();
    int base = blockIdx.x * EPB_A;
    int d[8];
    #pragma unroll
    for (int j = 0; j < 8; ++j) {
        int i = base + j * 256 + tid;
        d[j] = (i < E) ? dst[i] : -1;
        if (d[j] >= 0) atomicAdd(&lh[d[j] >> 8], 1);
    }
    __syncthreads();
    for (int b = tid; b < NBUCK; b += 256) {
        int c = lh[b];
        lh[b] = c ? (b * BUCK_CAP + atomicAdd(&bucket_cnt[b], c)) : 0;
    }
    __syncthreads();
    #pragma unroll
    for (int j = 0; j < 8; ++j) {
        int i = base + j * 256 + tid;
        if (d[j] >= 0) {
            int slot = atomicAdd(&lh[d[j] >> 8], 1);
            uint rec = ((uint)f2bf(w[i]) << 16) | (uint)src[i];
            staging[slot] = make_int2((int)rec, d[j] & 255);
        }
    }
}

// ---------------------------------------------------------------------------
// bf16 MFMA GEMM body (global-A variant, used for GEMM1 only).
template<int NT, bool AF32>
__device__ __forceinline__ void gemm_body(const void* __restrict__ Ain,
                                          const ushort* __restrict__ BT,
                                          int M, int K, int Nout,
                                          ushort* __restrict__ Cout, int row0) {
    __shared__ ushort a_s[64 * 40];
    __shared__ ushort b_s[64 * NT * 40];
    int tid = threadIdx.x;
    int wave = tid >> 6, lane = tid & 63;
    int lr = lane & 15, lk = (lane >> 4) * 8;
    f32x4 acc[4][NT];
    #pragma unroll
    for (int mt = 0; mt < 4; ++mt)
        #pragma unroll
        for (int nt = 0; nt < NT; ++nt) acc[mt][nt] = (f32x4){0.f, 0.f, 0.f, 0.f};

    for (int k0 = 0; k0 < K; k0 += 32) {
        {   // A tile: 64 rows x 32 k, 8 elems/thread
            int r = tid >> 2, c8 = (tid & 3) * 8;
            int gr = row0 + r; if (gr >= M) gr = M - 1;  // clamp, store-guarded
            if (AF32) {
                const float* Af = (const float*)Ain;
                float4 v0 = *(const float4*)(Af + (size_t)gr * K + k0 + c8);
                float4 v1 = *(const float4*)(Af + (size_t)gr * K + k0 + c8 + 4);
                ushort4 o0, o1;
                o0.x = f2bf(v0.x); o0.y = f2bf(v0.y); o0.z = f2bf(v0.z); o0.w = f2bf(v0.w);
                o1.x = f2bf(v1.x); o1.y = f2bf(v1.y); o1.z = f2bf(v1.z); o1.w = f2bf(v1.w);
                *(ushort4*)(a_s + r * 40 + c8) = o0;
                *(ushort4*)(a_s + r * 40 + c8 + 4) = o1;
            } else {
                const ushort* Ab = (const ushort*)Ain;
                float4 v = *(const float4*)(Ab + (size_t)gr * K + k0 + c8);
                *(float4*)(a_s + r * 40 + c8) = v;
            }
        }
        #pragma unroll
        for (int i = 0; i < NT; ++i) {  // BT tile: 64*NT rows x 32 k
            int idx = tid * NT + i;
            int r = idx >> 2, c8 = (idx & 3) * 8;
            float4 v = *(const float4*)(BT + (size_t)r * K + k0 + c8);
            *(float4*)(b_s + r * 40 + c8) = v;
        }
        __syncthreads();
        bf16x8 bfr[NT];
        #pragma unroll
        for (int nt = 0; nt < NT; ++nt)
            bfr[nt] = *(const bf16x8*)(b_s + ((wave * NT + nt) * 16 + lr) * 40 + lk);
        #pragma unroll
        for (int mt = 0; mt < 4; ++mt) {
            bf16x8 afr = *(const bf16x8*)(a_s + (mt * 16 + lr) * 40 + lk);
            #pragma unroll
            for (int nt = 0; nt < NT; ++nt)
                acc[mt][nt] = __builtin_amdgcn_mfma_f32_16x16x32_bf16(
                    afr, bfr[nt], acc[mt][nt], 0, 0, 0);
        }
        __syncthreads();
    }
    // C/D layout: col = lane&15, row = (lane>>4)*4 + i
    int col0 = wave * NT * 16;
    #pragma unroll
    for (int mt = 0; mt < 4; ++mt) {
        int gr0 = row0 + mt * 16 + (lane >> 4) * 4;
        #pragma unroll
        for (int nt = 0; nt < NT; ++nt) {
            int gc = col0 + nt * 16 + lr;
            #pragma unroll
            for (int i = 0; i < 4; ++i) {
                int gr = gr0 + i;
                if (gr < M && gc < Nout)
                    Cout[(size_t)gr * Nout + gc] = f2bf(acc[mt][nt][i]);
            }
        }
    }
}

// ---------------------------------------------------------------------------
// K2: blocks [0, NBUCK) do self-contained per-bucket scan+scatter into FIXED
// windows (gaps never read -> no global prefix). Blocks [NBUCK, +782) run
// GEMM1 (x fp32 -> supA bf16), overlapping the CSR tail.
__global__ __launch_bounds__(256) void scan_gemm1(const int* __restrict__ bucket_cnt,
                                                  const int2* __restrict__ staging,
                                                  int2* __restrict__ rsp2,
                                                  uint* __restrict__ edges,
                                                  const float* __restrict__ x,
                                                  const ushort* __restrict__ BT1,
                                                  ushort* __restrict__ supA) {
    if ((int)blockIdx.x >= NBUCK) {
        gemm_body<2, true>(x, BT1, N_NODES, 256, 128, supA,
                           ((int)blockIdx.x - NBUCK) * 64);
        return;
    }
    __shared__ int hist[256];
    __shared__ int buf[256];
    __shared__ int lcur[256];
    int tid = threadIdx.x;
    hist[tid] = 0;
    __syncthreads();
    int b = blockIdx.x;
    int c = bucket_cnt[b];
    const int2* st = staging + (size_t)b * BUCK_CAP;
    for (int p = tid; p < c; p += 256) atomicAdd(&hist[st[p].y], 1);
    __syncthreads();
    int v = (hist[tid] + 7) & ~7;   // pad per-node count to multiple of 8
    buf[tid] = v;
    __syncthreads();
    #pragma unroll
    for (int off = 1; off < 256; off <<= 1) {
        int t = (tid >= off) ? buf[tid - off] : 0;
        __syncthreads();
        buf[tid] += t;
        __syncthreads();
    }
    int bb = b * BUCK_WIN;
    int ex = buf[tid] - v + bb;
    int i = b * 256 + tid;
    if (i < N_NODES) rsp2[i] = make_int2(ex, ex + v);
    lcur[tid] = ex;
    __syncthreads();
    int e0 = bb + buf[255];
    for (int p = bb + tid; p < e0; p += 256) edges[p] = 0;   // covers padding
    __syncthreads();
    for (int p = tid; p < c; p += 256) {
        int2 r = st[p];
        int slot = atomicAdd(&lcur[r.y], 1);
        edges[slot] = (uint)r.x;
    }
}

// ---------------------------------------------------------------------------
// Fused [SpMM(F=128) + bias + relu] -> LDS A-tile -> [MFMA GEMM x BT].
// One block = 64 output rows. Each wave gathers 16 nodes (round-0 8-deep
// gather body, one vmem per edge), packs its two features straight into the
// MFMA-ready k-subtile layout a4_s[ks][row*40 + kk]. One __syncthreads, then
// the K-loop reads A from LDS and B fragments directly from the L2-hot BT.
// Eliminates the h-matrix global round-trip and a kernel boundary.
template<int NT>
__global__ __launch_bounds__(256) void fused_spmm_gemm(const uint* __restrict__ sup,
                                                       const int2* __restrict__ rsp2,
                                                       const uint* __restrict__ edges,
                                                       const float* __restrict__ bias,
                                                       const ushort* __restrict__ BT,
                                                       int Nout,
                                                       ushort* __restrict__ Cout) {
    __shared__ ushort a4_s[4][64 * 40];
    int tid = threadIdx.x;
    int wave = tid >> 6, lane = tid & 63;
    int row0 = blockIdx.x * 64;
    float bx = bias[2 * lane], by = bias[2 * lane + 1];
    int ks = lane >> 4;            // which 32-k subtile this lane's features fall in
    int kk = 2 * (lane & 15);      // k offset within the subtile
    for (int i = 0; i < 16; ++i) {
        int node = row0 + wave * 16 + i;
        int nd = (node < N_NODES) ? node : (N_NODES - 1);  // clamp; GEMM store guarded
        int2 ke = rsp2[nd];
        int k = ke.x, e = ke.y;
        f32x2 acc2 = (f32x2){0.f, 0.f};
        if (k < e) {
            const uint4* q4 = (const uint4*)(edges + k);
            uint4 qa = q4[0], qb = q4[1];
            for (; k < e; k += 8) {
                int kn = k + 8;
                int kc = (kn < e) ? kn : k;          // clamp: reload current (L1 hit)
                const uint4* n4 = (const uint4*)(edges + kc);
                uint4 na = n4[0], nb = n4[1];        // prefetch next group
                uint q[8] = {qa.x, qa.y, qa.z, qa.w, qb.x, qb.y, qb.z, qb.w};
                uint p[8];
                #pragma unroll
                for (int j = 0; j < 8; ++j)
                    p[j] = sup[(size_t)(q[j] & 0xffffu) * 64 + lane];
                #pragma unroll
                for (int j = 0; j < 8; ++j) {
                    float w = __uint_as_float(q[j] & 0xffff0000u);  // bf16 bits -> f32
                    f32x2 v;
                    v.x = __uint_as_float(p[j] << 16);
                    v.y = __uint_as_float(p[j] & 0xffff0000u);
                    acc2 += v * (f32x2){w, w};
                }
                qa = na; qb = nb;
            }
        }
        uint pk = ((uint)f2bf(fmaxf(acc2.y + by, 0.f)) << 16)
                |  (uint)f2bf(fmaxf(acc2.x + bx, 0.f));
        *(uint*)(&a4_s[ks][(wave * 16 + i) * 40 + kk]) = pk;
    }
    __syncthreads();
    // GEMM: C[64 x Nout] = A(LDS) @ BT^T, K = 128.
    int lr = lane & 15, lk = (lane >> 4) * 8;
    f32x4 acc[4][NT];
    #pragma unroll
    for (int mt = 0; mt < 4; ++mt)
        #pragma unroll
        for (int nt = 0; nt < NT; ++nt) acc[mt][nt] = (f32x4){0.f, 0.f, 0.f, 0.f};
    #pragma unroll
    for (int ksi = 0; ksi < 4; ++ksi) {
        int k0 = ksi * 32;
        bf16x8 bfr[NT];
        #pragma unroll
        for (int nt = 0; nt < NT; ++nt)
            bfr[nt] = *(const bf16x8*)(BT +
                (size_t)((wave * NT + nt) * 16 + lr) * 128 + k0 + lk);
        #pragma unroll
        for (int mt = 0; mt < 4; ++mt) {
            bf16x8 afr = *(const bf16x8*)(&a4_s[ksi][(mt * 16 + lr) * 40 + lk]);
            #pragma unroll
            for (int nt = 0; nt < NT; ++nt)
                acc[mt][nt] = __builtin_amdgcn_mfma_f32_16x16x32_bf16(
                    afr, bfr[nt], acc[mt][nt], 0, 0, 0);
        }
    }
    int col0 = wave * NT * 16;
    #pragma unroll
    for (int mt = 0; mt < 4; ++mt) {
        int gr0 = row0 + mt * 16 + (lane >> 4) * 4;
        #pragma unroll
        for (int nt = 0; nt < NT; ++nt) {
            int gc = col0 + nt * 16 + lr;
            #pragma unroll
            for (int i = 0; i < 4; ++i) {
                int gr = gr0 + i;
                if (gr < N_NODES && gc < Nout)
                    Cout[(size_t)gr * Nout + gc] = f2bf(acc[mt][nt][i]);
            }
        }
    }
}

// ---------------------------------------------------------------------------
// Layer 3: bf16 F=40 segment-sum + bias + log_softmax fused -> out (fp32)
__global__ __launch_bounds__(256) void spmm40_lsm(const ushort* __restrict__ sup,
                                                  const int2* __restrict__ rsp2,
                                                  const uint* __restrict__ edges,
                                                  const float* __restrict__ bias,
                                                  float* __restrict__ out, int n) {
    int wid = blockIdx.x * 4 + (threadIdx.x >> 6);
    int lane = threadIdx.x & 63;
    if (wid >= n) return;
    int2 ke = rsp2[wid];
    int k = ke.x, e = ke.y;
    float acc = 0.f;
    int lf = (lane < 40) ? lane : 39;  // inactive lanes read lane 39 (no OOB)
    if (k < e) {
        const uint4* q4 = (const uint4*)(edges + k);
        uint4 qa = q4[0], qb = q4[1];
        for (; k < e; k += 8) {
            int kn = k + 8;
            int kc = (kn < e) ? kn : k;
            const uint4* n4 = (const uint4*)(edges + kc);
            uint4 na = n4[0], nb4 = n4[1];
            uint q[8] = {qa.x, qa.y, qa.z, qa.w, qb.x, qb.y, qb.z, qb.w};
            float p[8];
            #pragma unroll
            for (int j = 0; j < 8; ++j) {
                uint us = sup[(size_t)(q[j] & 0xffffu) * 40 + lf];
                p[j] = __uint_as_float(us << 16);
            }
            #pragma unroll
            for (int j = 0; j < 8; ++j)
                acc += p[j] * __uint_as_float(q[j] & 0xffff0000u);
            qa = na; qb = nb4;
        }
    }
    float v = (lane < 40) ? acc + bias[lane] : -INFINITY;
    float m = v;
    #pragma unroll
    for (int off = 32; off; off >>= 1) m = fmaxf(m, __shfl_xor(m, off, 64));
    float ex = (lane < 40) ? expf(v - m) : 0.f;
    float s = ex;
    #pragma unroll
    for (int off = 32; off; off >>= 1) s += __shfl_xor(s, off, 64);
    float ls = logf(s);
    if (lane < 40) out[(size_t)wid * 40 + lane] = v - m - ls;
}

// ---------------------------------------------------------------------------
extern "C" void kernel_launch(void* const* d_in, const int* in_sizes, int n_in,
                              void* d_out, int out_size, void* d_ws, size_t ws_size,
                              hipStream_t stream) {
    const float* x   = (const float*)d_in[0];
    const float* ew  = (const float*)d_in[1];
    const float* W1  = (const float*)d_in[2];
    const float* b1  = (const float*)d_in[3];
    const float* W2  = (const float*)d_in[4];
    const float* b2  = (const float*)d_in[5];
    const float* W3  = (const float*)d_in[6];
    const float* b3  = (const float*)d_in[7];
    const int* esrc  = (const int*)d_in[8];
    const int* edst  = (const int*)d_in[9];
    float* out = (float*)d_out;

    char* ws = (char*)d_ws;
    size_t off = 0;
    auto alloc = [&](size_t bytes) {
        size_t cur = off;
        off += (bytes + 255) & ~(size_t)255;
        return cur;
    };
    int* bucket_cnt = (int*)(ws + alloc(256 * sizeof(int)));
    int2* rsp2   = (int2*)(ws + alloc((size_t)N_NODES * sizeof(int2)));          // 400 KB
    uint* edges  = (uint*)(ws + alloc((size_t)NBUCK * BUCK_WIN * sizeof(uint))); // 4.6 MB
    int2* staging = (int2*)(ws + alloc((size_t)NBUCK * BUCK_CAP * sizeof(int2))); // 6.4 MB
    ushort* BT1  = (ushort*)(ws + alloc(128 * 256 * 2));
    ushort* BT2  = (ushort*)(ws + alloc(128 * 128 * 2));
    ushort* BT3  = (ushort*)(ws + alloc(64 * 128 * 2));
    char* Sreg   = ws + alloc((size_t)N_NODES * 128 * 2);       // 12.8 MB
    char* Hreg   = ws + alloc((size_t)N_NODES * 128 * 2);       // 12.8 MB

    ushort* supA = (ushort*)Sreg;                  // gemm1 out
    ushort* supB = (ushort*)Hreg;                  // fused ag2 out
    ushort* sup3 = (ushort*)Sreg;                  // fused ag3 out (supA dead), 40/row

    hipMemsetAsync(bucket_cnt, 0, 256 * sizeof(int), stream);
    // K1: edge binning || weight conversion
    binA_cvtw<<<BINA_BLOCKS + CVTW_BLOCKS, 256, 0, stream>>>(
        esrc, edst, ew, bucket_cnt, staging, N_EDGES, W1, W2, W3, BT1, BT2, BT3);
    // K2: per-bucket scan+scatter (fixed windows) || GEMM1
    scan_gemm1<<<NBUCK + GEMM_BLOCKS, 256, 0, stream>>>(
        bucket_cnt, staging, rsp2, edges, x, BT1, supA);
    // K3: [agg1 + b1 + relu] -> GEMM x BT2 -> supB   (hA never hits global)
    fused_spmm_gemm<2><<<GEMM_BLOCKS, 256, 0, stream>>>(
        (const uint*)supA, rsp2, edges, b1, BT2, 128, supB);
    // K4: [agg2 + b2 + relu] -> GEMM x BT3 -> sup3 (40/row)
    fused_spmm_gemm<1><<<GEMM_BLOCKS, 256, 0, stream>>>(
        (const uint*)supB, rsp2, edges, b2, BT3, 40, sup3);
    // K5: agg3 + b3 + log_softmax -> out
    spmm40_lsm<<<(N_NODES + 3) / 4, 256, 0, stream>>>(sup3, rsp2, edges, b3,
                                                      out, N_NODES);
}